// Round 4
// baseline (212.083 us; speedup 1.0000x reference)
//
#include <hip/hip_runtime.h>

#define N_ROWS 16384
#define NCB    16
#define CB     1024
#define HALF   512          // codewords scanned per thread
#define RPB    128          // rows per block

// Zeros the 4 scalar tail outputs (rate_uem accumulator + 3 literal zeros).
__global__ void zero_tail_kernel(float* p) {
    int t = threadIdx.x;
    if (t < 4) p[t] = 0.0f;
}

// Per group a: softmax over logits -> cnb = ||c||^2 + (-log2 pmf)/lambda,
// l2u = -log2 pmf. One block per group.
__global__ __launch_bounds__(256) void prep_kernel(
    const float4* __restrict__ cbook,
    const float*  __restrict__ logits,
    const float*  __restrict__ lmbda_p,
    float* __restrict__ ws_cnb,
    float* __restrict__ ws_l2u)
{
    const int a = blockIdx.x;
    const int t = threadIdx.x;
    __shared__ float sredA[4], sredB[4];

    float l[4];
    float m = -INFINITY;
#pragma unroll
    for (int r = 0; r < 4; ++r) {
        l[r] = logits[a * CB + t + 256 * r];
        m = fmaxf(m, l[r]);
    }
#pragma unroll
    for (int off = 32; off >= 1; off >>= 1) m = fmaxf(m, __shfl_down(m, off, 64));
    if ((t & 63) == 0) sredA[t >> 6] = m;
    __syncthreads();
    const float gmax = fmaxf(fmaxf(sredA[0], sredA[1]), fmaxf(sredA[2], sredA[3]));

    float s = 0.f;
#pragma unroll
    for (int r = 0; r < 4; ++r) s += __expf(l[r] - gmax);
#pragma unroll
    for (int off = 32; off >= 1; off >>= 1) s += __shfl_down(s, off, 64);
    if ((t & 63) == 0) sredB[t >> 6] = s;
    __syncthreads();
    const float lse   = gmax + __logf(sredB[0] + sredB[1] + sredB[2] + sredB[3]);
    const float inv_l = 1.0f / lmbda_p[0];
    const float INV_LN2 = 1.4426950408889634f;
#pragma unroll
    for (int r = 0; r < 4; ++r) {
        int i = t + 256 * r;
        float4 w = cbook[a * CB + i];
        float v  = (lse - l[r]) * INV_LN2;           // -log2 pmf  (>= 0)
        ws_l2u[a * CB + i] = v;
        ws_cnb[a * CB + i] = w.x * w.x + w.y * w.y + w.z * w.z + w.w * w.w
                           + v * inv_l;              // ||c||^2 + rate_bias
    }
}

// Block: (128 rows, 2 codebook-halves) = 256 threads, 4 waves.
// Grid (16, 128) = 2048 blocks -> 8 blocks/CU -> 32 waves/CU (8/SIMD).
__global__ __launch_bounds__(256) void ecvq_kernel(
    const float4* __restrict__ x,       // (N*NCB) float4 rows
    const float4* __restrict__ cbook,   // (NCB*CB) float4 codewords
    const float*  __restrict__ ws_cnb,  // (NCB*CB) ||c||^2 + rate_bias
    const float*  __restrict__ ws_l2u,  // (NCB*CB) -log2 pmf
    float4* __restrict__ xhat,          // (N*NCB) float4
    float*  __restrict__ tail)
{
    const int a  = blockIdx.x;          // codebook group
    const int tx = threadIdx.x;         // row in block 0..127
    const int h  = threadIdx.y;         // codebook half 0..1
    const int n  = blockIdx.y * RPB + tx;

    const float4 xv = x[n * NCB + a];
    const float4 xm2 = make_float4(-2.f * xv.x, -2.f * xv.y,
                                   -2.f * xv.z, -2.f * xv.w);

    const int cbase = h * HALF;         // uniform per wave
    const float4* __restrict__ cb  = cbook  + a * CB + cbase;
    const float*  __restrict__ cnb = ws_cnb + a * CB + cbase;

    float dmin = INFINITY;
    int   imin = cbase;
    // Minimal 7-op iteration: 4 fma (base-seeded) + cmp + cndmask + min.
#pragma unroll 16
    for (int c = 0; c < HALF; ++c) {
        const float4 w = cb[c];         // wave-uniform -> scalar loads
        float d = fmaf(xm2.x, w.x, cnb[c]);
        d = fmaf(xm2.y, w.y, d);
        d = fmaf(xm2.z, w.z, d);
        d = fmaf(xm2.w, w.w, d);
        imin = (d < dmin) ? (cbase + c) : imin;   // strict '<': first index
        dmin = fminf(dmin, d);
    }

    // combine halves: half-0 wins ties (lower indices) to match argmin
    __shared__ float s_d[RPB];
    __shared__ int   s_i[RPB];
    if (h == 1) { s_d[tx] = dmin; s_i[tx] = imin; }
    __syncthreads();

    float rsum = 0.f;
    if (h == 0) {
        float d1 = s_d[tx];
        if (d1 < dmin) { dmin = d1; imin = s_i[tx]; }
        xhat[n * NCB + a] = cbook[a * CB + imin];   // gather winner
        rsum = ws_l2u[a * CB + imin];
    }

    // block-wide rate reduction (h==1 lanes contribute 0)
#pragma unroll
    for (int off = 32; off >= 1; off >>= 1) rsum += __shfl_down(rsum, off, 64);
    __shared__ float wsum[4];
    const int lin = tx + RPB * h;
    if ((lin & 63) == 0) wsum[lin >> 6] = rsum;
    __syncthreads();
    if (lin == 0)
        atomicAdd(&tail[0], wsum[0] + wsum[1] + wsum[2] + wsum[3]);
}

extern "C" void kernel_launch(void* const* d_in, const int* in_sizes, int n_in,
                              void* d_out, int out_size, void* d_ws, size_t ws_size,
                              hipStream_t stream) {
    (void)in_sizes; (void)n_in; (void)out_size; (void)ws_size;
    const float4* x      = (const float4*)d_in[0];
    const float4* cbook  = (const float4*)d_in[1];
    const float*  logits = (const float*)d_in[2];
    const float*  lmbda  = (const float*)d_in[3];

    float* out  = (float*)d_out;
    float* tail = out + (size_t)N_ROWS * NCB * 4;   // offset 1048576

    float* ws_cnb = (float*)d_ws;                   // 16*1024 floats
    float* ws_l2u = ws_cnb + NCB * CB;              // 16*1024 floats

    zero_tail_kernel<<<1, 64, 0, stream>>>(tail);
    prep_kernel<<<NCB, 256, 0, stream>>>(cbook, logits, lmbda, ws_cnb, ws_l2u);

    dim3 block(RPB, 2);                             // 256 threads
    dim3 grid(NCB, N_ROWS / RPB);                   // (16, 128) = 2048 blocks
    ecvq_kernel<<<grid, block, 0, stream>>>(x, cbook, ws_cnb, ws_l2u,
                                            (float4*)d_out, tail);
}

// Round 5
// 175.963 us; speedup vs baseline: 1.2053x; 1.2053x over previous
//
#include <hip/hip_runtime.h>

#define N_ROWS   16384
#define NCB      16
#define CB       1024
#define SLICES   8
#define SLICE_CW (CB / SLICES)   // 128 codewords per block
#define RPT      4               // rows per thread
#define TPB      256

// Init: packed (dist|idx) slots to ~0ULL (first 8B of each 16B xhat slot),
// and zero the 4 scalar tail outputs.
__global__ __launch_bounds__(256) void init_kernel(unsigned long long* xh64,
                                                   float* tail) {
    const int idx = blockIdx.x * 256 + threadIdx.x;   // 0..262143
    xh64[(size_t)idx * 2] = ~0ULL;
    if (blockIdx.x == 0 && threadIdx.x < 4) tail[threadIdx.x] = 0.0f;
}

// Per group a: softmax over logits -> cnb = ||c||^2 + (-log2 pmf)/lambda,
// l2u = -log2 pmf. One block per group.
__global__ __launch_bounds__(256) void prep_kernel(
    const float4* __restrict__ cbook,
    const float*  __restrict__ logits,
    const float*  __restrict__ lmbda_p,
    float* __restrict__ ws_cnb,
    float* __restrict__ ws_l2u)
{
    const int a = blockIdx.x;
    const int t = threadIdx.x;
    __shared__ float sredA[4], sredB[4];

    float l[4];
    float m = -INFINITY;
#pragma unroll
    for (int r = 0; r < 4; ++r) {
        l[r] = logits[a * CB + t + 256 * r];
        m = fmaxf(m, l[r]);
    }
#pragma unroll
    for (int off = 32; off >= 1; off >>= 1) m = fmaxf(m, __shfl_down(m, off, 64));
    if ((t & 63) == 0) sredA[t >> 6] = m;
    __syncthreads();
    const float gmax = fmaxf(fmaxf(sredA[0], sredA[1]), fmaxf(sredA[2], sredA[3]));

    float s = 0.f;
#pragma unroll
    for (int r = 0; r < 4; ++r) s += __expf(l[r] - gmax);
#pragma unroll
    for (int off = 32; off >= 1; off >>= 1) s += __shfl_down(s, off, 64);
    if ((t & 63) == 0) sredB[t >> 6] = s;
    __syncthreads();
    const float lse   = gmax + __logf(sredB[0] + sredB[1] + sredB[2] + sredB[3]);
    const float inv_l = 1.0f / lmbda_p[0];
    const float INV_LN2 = 1.4426950408889634f;
#pragma unroll
    for (int r = 0; r < 4; ++r) {
        int i = t + 256 * r;
        float4 w = cbook[a * CB + i];
        float v  = (lse - l[r]) * INV_LN2;           // -log2 pmf  (>= 0)
        ws_l2u[a * CB + i] = v;
        ws_cnb[a * CB + i] = w.x * w.x + w.y * w.y + w.z * w.z + w.w * w.w
                           + v * inv_l;              // ||c||^2 + rate_bias
    }
}

// Scan: grid (8 slices, 16 row-chunks, 16 groups) = 2048 blocks, 256 thr.
// Codeword addresses depend ONLY on blockIdx -> compiler emits scalar loads.
// 4 rows/thread amortize per-codeword overhead; 8 blocks/CU hide latency.
__global__ __launch_bounds__(TPB) void scan_kernel(
    const float4* __restrict__ x,        // (N*NCB) float4 rows
    const float4* __restrict__ cbook,    // (NCB*CB) float4 codewords
    const float*  __restrict__ ws_cnb,   // (NCB*CB) ||c||^2 + rate_bias
    unsigned long long* __restrict__ out64) // packed slots (stride 2 u64)
{
    const int slice = blockIdx.x;
    const int chunk = blockIdx.y;
    const int a     = blockIdx.z;
    const int tx    = threadIdx.x;
    const int cbase = slice * SLICE_CW;   // uniform (blockIdx-derived)

    int    n[RPT];
    float4 xm2[RPT];
    float  xn2[RPT];
#pragma unroll
    for (int r = 0; r < RPT; ++r) {
        n[r] = chunk * (TPB * RPT) + r * TPB + tx;
        float4 xv = x[n[r] * NCB + a];
        xm2[r] = make_float4(-2.f * xv.x, -2.f * xv.y, -2.f * xv.z, -2.f * xv.w);
        xn2[r] = xv.x * xv.x + xv.y * xv.y + xv.z * xv.z + xv.w * xv.w;
    }

    const float4* __restrict__ cb  = cbook  + a * CB + cbase;  // uniform
    const float*  __restrict__ cnb = ws_cnb + a * CB + cbase;  // uniform

    float dmin[RPT];
    int   imin[RPT];
#pragma unroll
    for (int r = 0; r < RPT; ++r) { dmin[r] = INFINITY; imin[r] = 0; }

#pragma unroll 4
    for (int c = 0; c < SLICE_CW; ++c) {
        const float4 w = cb[c];          // scalar (SMEM) loads
        const float  b = cnb[c];
        const int    cg = cbase + c;     // stays in SGPR
#pragma unroll
        for (int r = 0; r < RPT; ++r) {
            float d = fmaf(xm2[r].x, w.x, xn2[r]);   // seed ||x||^2 -> d >= 0
            d = fmaf(xm2[r].y, w.y, d);
            d = fmaf(xm2[r].z, w.z, d);
            d = fmaf(xm2[r].w, w.w, d);
            d += b;
            // inverted cmp so SGPR cg sits in cndmask src0 (1-SGPR rule)
            imin[r] = (d >= dmin[r]) ? imin[r] : cg; // strict '<' wins: first idx
            dmin[r] = fminf(dmin[r], d);
        }
    }

#pragma unroll
    for (int r = 0; r < RPT; ++r) {
        // d >= 0 -> float bits monotone as unsigned; low word = index so
        // equal distances resolve to the LOWER index (matches argmin).
        unsigned long long p =
            ((unsigned long long)__float_as_uint(dmin[r]) << 32) |
            (unsigned int)imin[r];
        atomicMin(&out64[(size_t)(n[r] * NCB + a) * 2], p);
    }
}

// Finish: unpack winner, gather codeword -> xhat, accumulate rate_uem.
__global__ __launch_bounds__(256) void finish_kernel(
    const float4* __restrict__ cbook,
    const float*  __restrict__ ws_l2u,
    float4* __restrict__ xhat,
    float*  __restrict__ tail)
{
    const int idx = blockIdx.x * 256 + threadIdx.x;   // (n*NCB + a)
    const int a   = idx & (NCB - 1);
    unsigned long long p = ((const unsigned long long*)xhat)[(size_t)idx * 2];
    const int im = (int)(p & 0xFFFFFFFFull);
    xhat[idx] = cbook[a * CB + im];                   // overwrite packed slot
    float r = ws_l2u[a * CB + im];
#pragma unroll
    for (int off = 32; off >= 1; off >>= 1) r += __shfl_down(r, off, 64);
    __shared__ float wsum[4];
    if ((threadIdx.x & 63) == 0) wsum[threadIdx.x >> 6] = r;
    __syncthreads();
    if (threadIdx.x == 0)
        atomicAdd(&tail[0], wsum[0] + wsum[1] + wsum[2] + wsum[3]);
}

extern "C" void kernel_launch(void* const* d_in, const int* in_sizes, int n_in,
                              void* d_out, int out_size, void* d_ws, size_t ws_size,
                              hipStream_t stream) {
    (void)in_sizes; (void)n_in; (void)out_size; (void)ws_size;
    const float4* x      = (const float4*)d_in[0];
    const float4* cbook  = (const float4*)d_in[1];
    const float*  logits = (const float*)d_in[2];
    const float*  lmbda  = (const float*)d_in[3];

    float* out  = (float*)d_out;
    float* tail = out + (size_t)N_ROWS * NCB * 4;     // offset 1048576

    float* ws_cnb = (float*)d_ws;                     // 16*1024 floats
    float* ws_l2u = ws_cnb + NCB * CB;                // 16*1024 floats

    init_kernel<<<N_ROWS * NCB / 256, 256, 0, stream>>>(
        (unsigned long long*)d_out, tail);
    prep_kernel<<<NCB, 256, 0, stream>>>(cbook, logits, lmbda, ws_cnb, ws_l2u);

    dim3 grid(SLICES, N_ROWS / (TPB * RPT), NCB);     // (8,16,16) = 2048 blocks
    scan_kernel<<<grid, TPB, 0, stream>>>(x, cbook, ws_cnb,
                                          (unsigned long long*)d_out);

    finish_kernel<<<N_ROWS * NCB / 256, 256, 0, stream>>>(
        cbook, ws_l2u, (float4*)d_out, tail);
}